// Round 4
// baseline (208.732 us; speedup 1.0000x reference)
//
#include <hip/hip_runtime.h>

#define BB 64
#define TT 512
#define HH 768
#define KK 11
#define START_ID 9
#define NEGV -10000.0f

typedef float vf2 __attribute__((ext_vector_type(2)));

// ---------------------------------------------------------------------------
// DPP wave-64 sum reduction: row_shr 1/2/4/8 + row_bcast:15 + row_bcast:31.
// Result lands in lane 63. VALU-path only (no LDS).
// ---------------------------------------------------------------------------
template <int CTRL>
__device__ __forceinline__ float dpp_add(float x) {
    int yi = __builtin_amdgcn_update_dpp(0, __float_as_int(x), CTRL, 0xF, 0xF, false);
    return x + __int_as_float(yi);
}

__device__ __forceinline__ float wave_sum_to_lane63(float x) {
    x = dpp_add<0x111>(x);  // row_shr:1
    x = dpp_add<0x112>(x);  // row_shr:2
    x = dpp_add<0x114>(x);  // row_shr:4
    x = dpp_add<0x118>(x);  // row_shr:8  -> lane15 of each row16 = row sum
    x = dpp_add<0x142>(x);  // row_bcast:15
    x = dpp_add<0x143>(x);  // row_bcast:31 -> lane63 = full sum
    return x;
}

__device__ __forceinline__ float rlane(float v, int l) {
    return __int_as_float(__builtin_amdgcn_readlane(__float_as_int(v), l));
}

// ---------------------------------------------------------------------------
// FC: feats[row,k] = dot(embeds[row,:], W[k,:]) + b[k].  One wave per row,
// 8 consecutive rows per wave, ONE row per iteration. Live state kept small
// (~165 VGPR: wf 132 + e 12 + acc 11) to stay far from the spill cliff and
// allow 3 waves/SIMD. Loads: 3x 1KB coalesced float4 per row.
// ---------------------------------------------------------------------------
__global__ __launch_bounds__(256) void fc_kernel(const float* __restrict__ embeds,
                                                 const float* __restrict__ W,
                                                 const float* __restrict__ bias,
                                                 float* __restrict__ feats) {
    const int lane = threadIdx.x & 63;
    const int wave_id = (blockIdx.x * blockDim.x + threadIdx.x) >> 6;

    float4 wf[KK][3];
#pragma unroll
    for (int k = 0; k < KK; ++k)
#pragma unroll
        for (int r = 0; r < 3; ++r)
            wf[k][r] = *reinterpret_cast<const float4*>(W + k * HH + r * 256 + lane * 4);

    float bk[KK];
#pragma unroll
    for (int k = 0; k < KK; ++k) bk[k] = bias[k];  // uniform -> SGPRs

    const int base = wave_id * 8;
#pragma unroll 1
    for (int rr = 0; rr < 8; ++rr) {
        const float* e = embeds + (size_t)(base + rr) * HH;
        float4 e0 = *reinterpret_cast<const float4*>(e + 0   + lane * 4);
        float4 e1 = *reinterpret_cast<const float4*>(e + 256 + lane * 4);
        float4 e2 = *reinterpret_cast<const float4*>(e + 512 + lane * 4);

        vf2 va[6] = {{e0.x, e0.y}, {e0.z, e0.w}, {e1.x, e1.y},
                     {e1.z, e1.w}, {e2.x, e2.y}, {e2.z, e2.w}};

        float acc[KK];
#pragma unroll
        for (int k = 0; k < KK; ++k) {
            vf2 wv0 = {wf[k][0].x, wf[k][0].y}, wv1 = {wf[k][0].z, wf[k][0].w};
            vf2 wv2 = {wf[k][1].x, wf[k][1].y}, wv3 = {wf[k][1].z, wf[k][1].w};
            vf2 wv4 = {wf[k][2].x, wf[k][2].y}, wv5 = {wf[k][2].z, wf[k][2].w};
            vf2 s = va[0] * wv0;
            s += va[1] * wv1;
            s += va[2] * wv2;
            s += va[3] * wv3;
            s += va[4] * wv4;
            s += va[5] * wv5;
            acc[k] = s.x + s.y;
        }
#pragma unroll
        for (int k = 0; k < KK; ++k) acc[k] = wave_sum_to_lane63(acc[k]);

        if (lane == 63) {
            float* o = feats + (size_t)(base + rr) * KK;
#pragma unroll
            for (int k = 0; k < KK; ++k) o[k] = acc[k] + bk[k];
        }
    }
}

// ---------------------------------------------------------------------------
// Viterbi: one block (256 thr) per batch.  (unchanged from R3 — passing,
// absmax 0; structural floor is the 511-step dependent chain in phase 1)
// ---------------------------------------------------------------------------
__global__ __launch_bounds__(256) void viterbi_kernel(const float* __restrict__ feats,
                                                      const float* __restrict__ trans,
                                                      float* __restrict__ out) {
    __shared__ __align__(16) float feats_lds[(TT + 4) * KK];  // +4 pad rows for ring
    __shared__ __align__(16) float dh[(TT - 1) * 12];         // stride 12 (48B)
    __shared__ int psi_lds[(TT - 1) * KK];
    __shared__ float tr_lds[KK * KK];
    __shared__ int comp[15 * KK];
    __shared__ int bt[16];
    __shared__ int sh_last;

    const int tid = threadIdx.x;
    const int b = blockIdx.x;

    {
        const float4* src = reinterpret_cast<const float4*>(feats + (size_t)b * TT * KK);
        float4* dst = reinterpret_cast<float4*>(feats_lds);
        for (int i = tid; i < TT * KK / 4; i += 256) dst[i] = src[i];
        if (tid < KK * KK) tr_lds[tid] = trans[tid];
    }
    __syncthreads();

    // ---- Phase 1: forward (wave 0 only) ----
    if (tid < 64) {
        const int i = tid;
        const int ci = (i < KK) ? i : 0;
        float tr[KK];
#pragma unroll
        for (int j = 0; j < KK; ++j) tr[j] = (i < KK) ? tr_lds[i * KK + j] : NEGV;

        float delta = (i == START_ID) ? 0.0f : NEGV;

        auto vstep = [&](int t, float fcur) {
            if (i < KK) dh[(t - 1) * 12 + i] = delta;   // pre-step delta (off-chain)
            float dj[KK];
#pragma unroll
            for (int j = 0; j < KK; ++j) dj[j] = rlane(delta, j);
            float s[KK];
#pragma unroll
            for (int j = 0; j < KK; ++j) s[j] = tr[j] + dj[j];
            float t0 = fmaxf(fmaxf(s[0], s[1]), s[2]);
            float t1 = fmaxf(fmaxf(s[3], s[4]), s[5]);
            float t2 = fmaxf(fmaxf(s[6], s[7]), s[8]);
            float t3 = fmaxf(s[9], s[10]);
            float best = fmaxf(fmaxf(fmaxf(t0, t1), t2), t3);
            delta = best + fcur;
        };

        float fr0 = feats_lds[1 * KK + ci];
        float fr1 = feats_lds[2 * KK + ci];
        float fr2 = feats_lds[3 * KK + ci];
        float fr3 = feats_lds[4 * KK + ci];

        int t = 1;
#pragma unroll 1
        for (; t <= TT - 4; t += 4) {
            vstep(t,     fr0); fr0 = feats_lds[(t + 4) * KK + ci];
            vstep(t + 1, fr1); fr1 = feats_lds[(t + 5) * KK + ci];
            vstep(t + 2, fr2); fr2 = feats_lds[(t + 6) * KK + ci];
            vstep(t + 3, fr3); fr3 = feats_lds[(t + 7) * KK + ci];
        }
        // t == 509: remaining steps 509,510,511
        vstep(TT - 3, fr0);
        vstep(TT - 2, fr1);
        vstep(TT - 1, fr2);

        // score + last tag (strict-first argmax, exact)
        float dfin[KK];
#pragma unroll
        for (int j = 0; j < KK; ++j) dfin[j] = rlane(delta, j);
        float best = dfin[0];
        int last = 0;
#pragma unroll
        for (int j = 1; j < KK; ++j) {
            bool c = dfin[j] > best;
            best = c ? dfin[j] : best;
            last = c ? j : last;
        }
        if (tid == 0) {
            out[b] = best;
            out[BB + (size_t)b * TT + (TT - 1)] = (float)last;
            sh_last = last;
        }
    }
    __syncthreads();

    // ---- Phase 2: psi recompute, parallel over (s, i) ----
    {
        const int i = tid & 15;
        const int sg = tid >> 4;
        if (i < KK) {
            float tri[KK];
#pragma unroll
            for (int j = 0; j < KK; ++j) tri[j] = tr_lds[i * KK + j];
            for (int s = sg; s < TT - 1; s += 16) {
                const float4* dr = reinterpret_cast<const float4*>(dh + s * 12);
                float4 a = dr[0], c4 = dr[1], d4 = dr[2];
                float sc[KK] = {tri[0] + a.x,  tri[1] + a.y,  tri[2] + a.z,  tri[3] + a.w,
                                tri[4] + c4.x, tri[5] + c4.y, tri[6] + c4.z, tri[7] + c4.w,
                                tri[8] + d4.x, tri[9] + d4.y, tri[10] + d4.z};
                float bv = sc[0];
                int bj = 0;
#pragma unroll
                for (int j = 1; j < KK; ++j) {
                    bool c = sc[j] > bv;        // strict: first max wins
                    bv = c ? sc[j] : bv;
                    bj = c ? j : bj;
                }
                psi_lds[s * KK + i] = bj;
            }
        }
    }
    __syncthreads();

    // ---- Phase 3a: chunk composition walks (0..14) + chunk 15 real walk ----
    {
        const int c = tid >> 4;
        const int i = tid & 15;
        if (c < 15 && i < KK) {
            int cur = i;
            for (int s = c * 32 + 31; s >= c * 32; --s) cur = psi_lds[s * KK + cur];
            comp[c * KK + i] = cur;            // path[32c] given path[32(c+1)] = i
        } else if (c == 15 && i == 0) {
            int cur = sh_last;
            float* po = out + BB + (size_t)b * TT;
            for (int s = TT - 2; s >= 480; --s) {
                cur = psi_lds[s * KK + cur];
                po[s] = (float)cur;
            }
            bt[15] = cur;                      // = path[480]
        }
    }
    __syncthreads();

    // ---- Phase 3b: boundary chain ----
    if (tid == 0) {
        for (int c = 14; c >= 1; --c) bt[c] = comp[c * KK + bt[c + 1]];
    }
    __syncthreads();

    // ---- Phase 3c: parallel re-walks, store path ----
    if (tid < 15) {
        const int c = tid;
        int cur = bt[c + 1];                   // path[32(c+1)]
        float* po = out + BB + (size_t)b * TT;
        for (int s = c * 32 + 31; s >= c * 32; --s) {
            cur = psi_lds[s * KK + cur];
            po[s] = (float)cur;
        }
    }
}

extern "C" void kernel_launch(void* const* d_in, const int* in_sizes, int n_in,
                              void* d_out, int out_size, void* d_ws, size_t ws_size,
                              hipStream_t stream) {
    const float* embeds = (const float*)d_in[0];  // [B,T,H]
    const float* W_fc   = (const float*)d_in[1];  // [K,H]
    const float* b_fc   = (const float*)d_in[2];  // [K]
    const float* trans  = (const float*)d_in[3];  // [K,K]
    float* out = (float*)d_out;                   // [B] score ++ [B,T] path (as float)
    float* feats = (float*)d_ws;                  // [B,T,K] scratch

    fc_kernel<<<1024, 256, 0, stream>>>(embeds, W_fc, b_fc, feats);
    viterbi_kernel<<<BB, 256, 0, stream>>>(feats, trans, out);
}